// Round 1
// baseline (610.085 us; speedup 1.0000x reference)
//
#include <hip/hip_runtime.h>

typedef __bf16 bf16x8 __attribute__((ext_vector_type(8)));
typedef float  f32x4  __attribute__((ext_vector_type(4)));

constexpr int Bn = 16, Cn = 256, Hn = 64, Wn = 64, HWn = 64 * 64;
constexpr int Ntot = Bn * HWn;  // 65536 pixels

#define DEV static __device__ __forceinline__

DEV unsigned short f2bf(float f) {
  unsigned u = __builtin_bit_cast(unsigned, f);
  u += 0x7fffu + ((u >> 16) & 1u);   // RNE
  return (unsigned short)(u >> 16);
}
DEV float bf2f(unsigned short s) {
  unsigned u = ((unsigned)s) << 16;
  return __builtin_bit_cast(float, u);
}
DEV bf16x8 asbf(uint4 u) { return __builtin_bit_cast(bf16x8, u); }

// ---------------- K0: weights -> bf16 ----------------
// A_qv[t][o][c]: o<256 -> q_w[o][c]; o>=256 -> kv{r,t}_w[o][c] (v rows of kv)
// A_off[t][o][tap][c]: t=0 offr_w, t=1 offt_w; o>=8 zero
// A_out[o][c2] = out_w
__global__ void k_prep(const float* qw, const float* kvrw, const float* kvtw,
                       const float* offrw, const float* offtw, const float* outw,
                       unsigned short* Aqv, unsigned short* Aoff, unsigned short* Aout) {
  int idx = blockIdx.x * 256 + threadIdx.x;
  if (idx < 2 * 512 * 256) {
    int t = idx >> 17; int r = idx & 131071; int o = r >> 8; int c = r & 255;
    float v = (o < 256) ? qw[o * 256 + c] : (t ? kvtw[o * 256 + c] : kvrw[o * 256 + c]);
    Aqv[idx] = f2bf(v);
    return;
  }
  idx -= 2 * 512 * 256;
  if (idx < 2 * 16 * 2304) {
    int t = idx / 36864; int r = idx % 36864;
    int o = r / 2304; int rc = r % 2304; int tap = rc >> 8; int c = rc & 255;
    const float* w = t ? offtw : offrw;
    float v = (o < 8) ? w[(o * 256 + c) * 9 + tap] : 0.f;
    Aoff[idx] = f2bf(v);
    return;
  }
  idx -= 2 * 16 * 2304;
  if (idx < 256 * 512) Aout[idx] = f2bf(outw[idx]);
}

// ---------------- K1: NCHW f32 -> NHWC bf16 transpose ----------------
__global__ void k_transpose(const float* rgb, const float* th, unsigned short* xT) {
  int bi = blockIdx.x;
  int ct = bi & 3;
  int nt = (bi >> 2) & 63;
  int b  = (bi >> 8) & 15;
  int t  = bi >> 12;
  const float* src = t ? th : rgb;
  int c0 = ct * 64, n0 = nt * 64;
  __shared__ float tile[64][65];
  int tid = threadIdx.x;
  int nl = tid & 63, cg = tid >> 6;
#pragma unroll
  for (int i = 0; i < 16; i++) {
    int c = cg * 16 + i;
    tile[c][nl] = src[(size_t)(b * 256 + c0 + c) * HWn + n0 + nl];
  }
  __syncthreads();
  int pr = tid >> 2, sg = tid & 3;
  unsigned short tmp[16];
#pragma unroll
  for (int j = 0; j < 16; j++) tmp[j] = f2bf(tile[sg * 16 + j][pr]);
  unsigned short* dst = xT + (size_t)t * Ntot * 256 +
                        (size_t)(b * HWn + n0 + pr) * 256 + c0 + sg * 16;
  *(uint4*)(dst)     = *(const uint4*)(tmp);
  *(uint4*)(dst + 8) = *(const uint4*)(tmp + 8);
}

// ---------------- K2: QV GEMM (M=512 split in 2, K=256, N=65536) ----------------
// out rows 0..255: sigmoid(q) -> qs[t]; rows 256..511: v + bias -> vv[t]  (NHWC bf16)
__global__ __launch_bounds__(512, 2) void k_qv(
    const unsigned short* Aqv, const unsigned short* xT,
    const float* qb, const float* kvrb, const float* kvtb,
    unsigned short* qs, unsigned short* vv) {
  __shared__ unsigned short Asm[2][256 * 64];  // 256 o-rows x 64 k, swizzled
  __shared__ unsigned short Xsm[2][128 * 64];  // 128 pix-rows x 64 k, swizzled
  int t  = blockIdx.z;
  int o0 = blockIdx.y * 256;
  int n0 = blockIdx.x * 128;
  int tid = threadIdx.x;
  const unsigned short* Aq = Aqv + t * 512 * 256;
  const unsigned short* Xg = xT + (size_t)t * Ntot * 256 + (size_t)n0 * 256;

  auto stage = [&](int kb, int bb) {
#pragma unroll
    for (int i = 0; i < 4; i++) {  // A: 2048 x 16B chunks
      int cid = tid + i * 512;
      int row = cid >> 3, seg = cid & 7;
      int ss = seg ^ (row & 7);
      uint4 val = *(const uint4*)(Aq + (o0 + row) * 256 + kb * 64 + ss * 8);
      *(uint4*)(&Asm[bb][row * 64 + seg * 8]) = val;
    }
#pragma unroll
    for (int i = 0; i < 2; i++) {  // X: 1024 x 16B chunks
      int cid = tid + i * 512;
      int row = cid >> 3, seg = cid & 7;
      int ss = seg ^ (row & 7);
      uint4 val = *(const uint4*)(Xg + row * 256 + kb * 64 + ss * 8);
      *(uint4*)(&Xsm[bb][row * 64 + seg * 8]) = val;
    }
  };

  int w = __builtin_amdgcn_readfirstlane(tid >> 6);
  int lane = tid & 63;
  int wo = w >> 1, wn = w & 1;
  int r16 = lane & 15, q4 = lane >> 4;

  f32x4 acc[4][4];
#pragma unroll
  for (int a = 0; a < 4; a++)
#pragma unroll
    for (int b2 = 0; b2 < 4; b2++) acc[a][b2] = f32x4{0.f, 0.f, 0.f, 0.f};

  stage(0, 0);
  __syncthreads();
#pragma unroll
  for (int kb = 0; kb < 4; kb++) {
    if (kb < 3) stage(kb + 1, (kb + 1) & 1);
    int bb = kb & 1;
#pragma unroll
    for (int ks = 0; ks < 2; ks++) {
      uint4 af[4], bfr[4];
#pragma unroll
      for (int oi = 0; oi < 4; oi++) {
        int row = wo * 64 + oi * 16 + r16;
        int seg = (ks * 4 + q4) ^ (row & 7);
        af[oi] = *(const uint4*)(&Asm[bb][row * 64 + seg * 8]);
      }
#pragma unroll
      for (int ni = 0; ni < 4; ni++) {
        int row = wn * 64 + ni * 16 + r16;
        int seg = (ks * 4 + q4) ^ (row & 7);
        bfr[ni] = *(const uint4*)(&Xsm[bb][row * 64 + seg * 8]);
      }
#pragma unroll
      for (int oi = 0; oi < 4; oi++)
#pragma unroll
        for (int ni = 0; ni < 4; ni++)
          acc[oi][ni] = __builtin_amdgcn_mfma_f32_16x16x32_bf16(
              asbf(af[oi]), asbf(bfr[ni]), acc[oi][ni], 0, 0, 0);
    }
    __syncthreads();
  }
  // epilogue
  const float* vb = t ? kvtb : kvrb;
  bool isq = (blockIdx.y == 0);
  unsigned short* outbase = isq ? (qs + (size_t)t * Ntot * 256)
                                : (vv + (size_t)t * Ntot * 256);
#pragma unroll
  for (int oi = 0; oi < 4; oi++) {
    int obase = o0 + wo * 64 + oi * 16 + q4 * 4;
#pragma unroll
    for (int ni = 0; ni < 4; ni++) {
      int n = n0 + wn * 64 + ni * 16 + r16;
      unsigned short pk[4];
#pragma unroll
      for (int j = 0; j < 4; j++) {
        float val = acc[oi][ni][j] + (isq ? qb[obase + j] : vb[obase + j]);
        if (isq) val = 1.f / (1.f + __expf(-val));
        pk[j] = f2bf(val);
      }
      *(uint2*)(outbase + (size_t)n * 256 + (obase & 255)) = *(const uint2*)(pk);
    }
  }
}

// ---------------- K3: 3x3 offset conv as GEMM (M=16 pad of 8, K=9*256) ----------------
// t=0: input th -> off_rgb2th (offr);  t=1: input rgb -> off_th2rgb (offt)
__global__ void k_off(const unsigned short* Aoff, const unsigned short* xT,
                      const float* offrb, const float* offtb, float* offo) {
  int t  = blockIdx.y;
  int bh = blockIdx.x;
  int b = bh >> 6, h = bh & 63;
  int tid = threadIdx.x, lane = tid & 63, w = tid >> 6;
  int r16 = lane & 15, q4 = lane >> 4;
  int wl = w * 16 + r16;  // pixel col 0..63
  const unsigned short* Aw  = Aoff + t * 36864;
  const unsigned short* xin = xT + (size_t)(t ? 0 : 1) * Ntot * 256;
  f32x4 acc = {0.f, 0.f, 0.f, 0.f};
#pragma unroll
  for (int tap = 0; tap < 9; tap++) {
    int dy = tap / 3 - 1, dx = tap % 3 - 1;
    int hh = h + dy, ww = wl + dx;
    bool valid = (hh >= 0 && hh < 64 && ww >= 0 && ww < 64);
    const unsigned short* bsrc =
        xin + (size_t)((b * 64 + (valid ? hh : 0)) * 64 + (valid ? ww : 0)) * 256 + q4 * 8;
#pragma unroll
    for (int ks = 0; ks < 8; ks++) {
      uint4 a = *(const uint4*)(Aw + (r16 * 9 + tap) * 256 + ks * 32 + q4 * 8);
      uint4 bv;
      if (valid) bv = *(const uint4*)(bsrc + ks * 32);
      else { bv.x = 0; bv.y = 0; bv.z = 0; bv.w = 0; }
      acc = __builtin_amdgcn_mfma_f32_16x16x32_bf16(asbf(a), asbf(bv), acc, 0, 0, 0);
    }
  }
  if (lane < 32) {  // rows 0..7 only
    const float* ob = t ? offtb : offrb;
    int n = (b * 64 + h) * 64 + wl;
    float4 r;
    r.x = acc[0] + ob[q4 * 4 + 0];
    r.y = acc[1] + ob[q4 * 4 + 1];
    r.z = acc[2] + ob[q4 * 4 + 2];
    r.w = acc[3] + ob[q4 * 4 + 3];
    *(float4*)(offo + (size_t)t * Ntot * 8 + (size_t)n * 8 + q4 * 4) = r;
  }
}

// ---------------- K4: deform + attn + final GEMM + skip + BN partials ----------------
__global__ __launch_bounds__(256, 2) void k_fused(
    const unsigned short* qs, const unsigned short* vv, const float* offo,
    const unsigned short* Aout, const float* outb,
    const float* rgb, const float* th,
    float* dout, float* partial) {
  __shared__ unsigned short concat[64 * 512];  // [pix][512ch] swizzled, bf16
  __shared__ float bstat[256][2];
  int tid = threadIdx.x;
  int bi = blockIdx.x;
  int b = bi >> 6, h = bi & 63;
  bstat[tid][0] = 0.f; bstat[tid][1] = 0.f;

  int pix = tid & 63, chunk = tid >> 6;  // chunk: 64 channels each
  int n = (b * 64 + h) * 64 + pix;
#pragma unroll
  for (int pass = 0; pass < 2; pass++) {
    // pass0 -> concat ch 0..255  = sig(q_rgb) * deform(v_th, off_th2rgb)
    // pass1 -> concat ch 256..511 = sig(q_th)  * deform(v_rgb, off_rgb2th)
    const unsigned short* vsrc = vv + (size_t)(pass ? 0 : 1) * Ntot * 256;
    const float* offp          = offo + (size_t)(pass ? 0 : 1) * Ntot * 8;
    const unsigned short* qsrc = qs + (size_t)(pass ? 1 : 0) * Ntot * 256;
    float acc[64];
#pragma unroll
    for (int i = 0; i < 64; i++) acc[i] = 0.f;
    for (int p = 0; p < 4; p++) {
      float dx = offp[(size_t)n * 8 + 2 * p], dy = offp[(size_t)n * 8 + 2 * p + 1];
      float xf = (float)pix + dx * (63.f / 64.f);
      float yf = (float)h   + dy * (63.f / 64.f);
      float x0f = floorf(xf), y0f = floorf(yf);
      float wx = xf - x0f, wy = yf - y0f;
      int x0 = (int)x0f, y0 = (int)y0f;
#pragma unroll
      for (int cc = 0; cc < 4; cc++) {
        int cy = cc >> 1, cx = cc & 1;
        int ix = x0 + cx, iy = y0 + cy;
        float wgt = (cx ? wx : 1.f - wx) * (cy ? wy : 1.f - wy);
        bool ok = (ix >= 0 && ix < 64 && iy >= 0 && iy < 64);
        if (ok) {
          const unsigned short* g =
              vsrc + (size_t)((b * 64 + iy) * 64 + ix) * 256 + chunk * 64;
#pragma unroll
          for (int s = 0; s < 8; s++) {
            uint4 raw = *(const uint4*)(g + s * 8);
            const unsigned short* rp = (const unsigned short*)&raw;
#pragma unroll
            for (int e = 0; e < 8; e++) acc[s * 8 + e] += wgt * bf2f(rp[e]);
          }
        }
      }
    }
    int segbase = pass * 32 + chunk * 8;
#pragma unroll
    for (int s = 0; s < 8; s++) {
      uint4 qraw = *(const uint4*)(qsrc + (size_t)n * 256 + chunk * 64 + s * 8);
      const unsigned short* qp = (const unsigned short*)&qraw;
      unsigned short pk[8];
#pragma unroll
      for (int e = 0; e < 8; e++) pk[e] = f2bf(0.25f * acc[s * 8 + e] * bf2f(qp[e]));
      int seg = (segbase + s) ^ (pix & 7);
      *(uint4*)(&concat[pix * 512 + seg * 8]) = *(const uint4*)(pk);
    }
  }
  __syncthreads();

  // phase 2: fused(256 x 64pix) = A_out(256x512) x concat(512x64)
  int lane = tid & 63, wv = tid >> 6;
  int wo = wv >> 1, wn = wv & 1;
  int r16 = lane & 15, q4 = lane >> 4;
  f32x4 acc2[8][2];
#pragma unroll
  for (int a = 0; a < 8; a++) { acc2[a][0] = f32x4{0.f,0.f,0.f,0.f}; acc2[a][1] = f32x4{0.f,0.f,0.f,0.f}; }
#pragma unroll
  for (int kst = 0; kst < 16; kst++) {
    uint4 bfr[2];
#pragma unroll
    for (int ni = 0; ni < 2; ni++) {
      int row = wn * 32 + ni * 16 + r16;
      int seg = (kst * 4 + q4) ^ (row & 7);
      bfr[ni] = *(const uint4*)(&concat[row * 512 + seg * 8]);
    }
#pragma unroll
    for (int oi = 0; oi < 8; oi++) {
      int o = wo * 128 + oi * 16 + r16;
      uint4 a = *(const uint4*)(Aout + (size_t)o * 512 + kst * 32 + q4 * 8);
      acc2[oi][0] = __builtin_amdgcn_mfma_f32_16x16x32_bf16(asbf(a), asbf(bfr[0]), acc2[oi][0], 0, 0, 0);
      acc2[oi][1] = __builtin_amdgcn_mfma_f32_16x16x32_bf16(asbf(a), asbf(bfr[1]), acc2[oi][1], 0, 0, 0);
    }
  }
  // epilogue: bias + skip + store + BN partials
#pragma unroll
  for (int oi = 0; oi < 8; oi++) {
    int ob = wo * 128 + oi * 16 + q4 * 4;
#pragma unroll
    for (int j = 0; j < 4; j++) {
      int o = ob + j;
      float s1 = 0.f, s2 = 0.f;
#pragma unroll
      for (int ni = 0; ni < 2; ni++) {
        int pl = wn * 32 + ni * 16 + r16;
        int hw = h * 64 + pl;
        size_t gidx = (size_t)(b * 256 + o) * HWn + hw;
        float val = acc2[oi][ni][j] + outb[o] + 0.5f * (rgb[gidx] + th[gidx]);
        dout[gidx] = val;
        s1 += val; s2 += val * val;
      }
#pragma unroll
      for (int m = 1; m < 16; m <<= 1) {
        s1 += __shfl_xor(s1, m, 16);
        s2 += __shfl_xor(s2, m, 16);
      }
      if (r16 == 0) { atomicAdd(&bstat[o][0], s1); atomicAdd(&bstat[o][1], s2); }
    }
  }
  __syncthreads();
  partial[(size_t)bi * 512 + tid]       = bstat[tid][0];
  partial[(size_t)bi * 512 + 256 + tid] = bstat[tid][1];
}

// ---------------- K5: reduce partials -> scale/shift ----------------
__global__ void k_stats(const float* partial, const float* gamma, const float* beta,
                        float* sstats) {
  int c = blockIdx.x, tid = threadIdx.x;
  float s1 = 0.f, s2 = 0.f;
  for (int i = tid; i < 1024; i += 256) {
    s1 += partial[(size_t)i * 512 + c];
    s2 += partial[(size_t)i * 512 + 256 + c];
  }
  __shared__ float r1[256], r2[256];
  r1[tid] = s1; r2[tid] = s2;
  __syncthreads();
  for (int st = 128; st > 0; st >>= 1) {
    if (tid < st) { r1[tid] += r1[tid + st]; r2[tid] += r2[tid + st]; }
    __syncthreads();
  }
  if (tid == 0) {
    float mean = r1[0] / 65536.f;
    float var  = r2[0] / 65536.f - mean * mean;
    float scale = gamma[c] / sqrtf(var + 1e-5f);
    sstats[c]       = scale;
    sstats[256 + c] = beta[c] - mean * scale;
  }
}

// ---------------- K6: BN apply in-place on d_out ----------------
__global__ void k_bn(float* dout, const float* sstats) {
  int idx = blockIdx.x * 256 + threadIdx.x;
  size_t base = (size_t)idx * 4;
  int c = (int)((base >> 12) & 255);
  float4 v = *(float4*)(dout + base);
  float sc = sstats[c], sh = sstats[256 + c];
  v.x = v.x * sc + sh; v.y = v.y * sc + sh;
  v.z = v.z * sc + sh; v.w = v.w * sc + sh;
  *(float4*)(dout + base) = v;
}

extern "C" void kernel_launch(void* const* d_in, const int* in_sizes, int n_in,
                              void* d_out, int out_size, void* d_ws, size_t ws_size,
                              hipStream_t stream) {
  const float* rgb   = (const float*)d_in[0];
  const float* th    = (const float*)d_in[1];
  const float* qw    = (const float*)d_in[2];
  const float* qb    = (const float*)d_in[3];
  const float* kvrw  = (const float*)d_in[4];
  const float* kvrb  = (const float*)d_in[5];
  const float* kvtw  = (const float*)d_in[6];
  const float* kvtb  = (const float*)d_in[7];
  const float* offrw = (const float*)d_in[8];
  const float* offrb = (const float*)d_in[9];
  const float* offtw = (const float*)d_in[10];
  const float* offtb = (const float*)d_in[11];
  const float* outw  = (const float*)d_in[12];
  const float* outb  = (const float*)d_in[13];
  const float* gamma = (const float*)d_in[14];
  const float* beta  = (const float*)d_in[15];
  float* dout = (float*)d_out;

  unsigned short* xT   = (unsigned short*)d_ws;                 // 2 * N * 256 bf16
  unsigned short* qsb  = xT  + (size_t)2 * Ntot * 256;          // 2 * N * 256 bf16
  unsigned short* vvb  = qsb + (size_t)2 * Ntot * 256;          // 2 * N * 256 bf16
  float* offo          = (float*)(vvb + (size_t)2 * Ntot * 256); // 2 * N * 8 f32
  unsigned short* Aqv  = (unsigned short*)(offo + (size_t)2 * Ntot * 8);
  unsigned short* Aoff = Aqv + 2 * 512 * 256;
  unsigned short* Aout = Aoff + 2 * 16 * 2304;
  float* partial       = (float*)(Aout + 256 * 512);            // 1024 * 512 f32
  float* sstats        = partial + (size_t)1024 * 512;          // 512 f32

  k_prep<<<1824, 256, 0, stream>>>(qw, kvrw, kvtw, offrw, offtw, outw, Aqv, Aoff, Aout);
  k_transpose<<<8192, 256, 0, stream>>>(rgb, th, xT);
  k_qv<<<dim3(512, 2, 2), 512, 0, stream>>>(Aqv, xT, qb, kvrb, kvtb, qsb, vvb);
  k_off<<<dim3(1024, 2), 256, 0, stream>>>(Aoff, xT, offrb, offtb, offo);
  k_fused<<<1024, 256, 0, stream>>>(qsb, vvb, offo, Aout, outb, rgb, th, dout, partial);
  k_stats<<<256, 256, 0, stream>>>(partial, gamma, beta, sstats);
  k_bn<<<16384, 256, 0, stream>>>(dout, sstats);
}